// Round 1
// baseline (772.707 us; speedup 1.0000x reference)
//
#include <hip/hip_runtime.h>

// ---------------------------------------------------------------------------
// BikeSafetyGNN: 3-layer GraphSAGE (mean) + 2 linear heads, fp32.
// R10: (a) deepen gather inner loop to 16 edges in flight (4x int4 adj +
//      16 uint2 P loads) — targets the latency-bound random-gather regime
//      (VALU 35%, HBM 45%, neither saturated; VGPR=32 leaves MLP headroom).
//      (b) fuse the two linear heads into gather<16> (kills k_head pass +
//      12.8 MB H3 re-read + one launch).
// R9: uint2 gather shape (16 lanes x 8 B = full 128 B row/node), T packed
//     to 4 B/edge, bcur zeroing folded into k_bscan.
// ---------------------------------------------------------------------------

typedef __bf16 bf16x8 __attribute__((ext_vector_type(8)));
typedef float  f32x4  __attribute__((ext_vector_type(4)));

__device__ __forceinline__ unsigned short f2bf_rne(float f) {
    unsigned int u = __float_as_uint(f);
    u = (u + 0x7FFFu + ((u >> 16) & 1u)) >> 16;
    return (unsigned short)u;
}

// unpack 4 bf16 (packed little-endian in uint2) and accumulate into float4
__device__ __forceinline__ void bfacc(float4& a, const uint2 q) {
    a.x += __uint_as_float(q.x << 16);
    a.y += __uint_as_float(q.x & 0xFFFF0000u);
    a.z += __uint_as_float(q.y << 16);
    a.w += __uint_as_float(q.y & 0xFFFF0000u);
}

// ---------------- CSR build (bucket = dst >> 10) ----------------

__global__ __launch_bounds__(256) void k_bcount(const int* __restrict__ dst, int E, int N,
                                                int* __restrict__ bcnt) {
    __shared__ int h[256];
    const int tid = threadIdx.x;
    h[tid] = 0;
    __syncthreads();
    const int stride = gridDim.x * 256;
    for (int i = blockIdx.x * 256 + tid; i < E; i += stride) {
        int d = dst[i];
        d = d < 0 ? 0 : (d >= N ? N - 1 : d);
        atomicAdd(&h[d >> 10], 1);
    }
    __syncthreads();
    if (h[tid]) atomicAdd(&bcnt[tid], h[tid]);
}

__global__ __launch_bounds__(256) void k_bscan(const int* __restrict__ bcnt,
                                               int* __restrict__ boff,
                                               int* __restrict__ bcur, int NBK, int E) {
    __shared__ int sd[256];
    const int tid = threadIdx.x;
    bcur[tid] = 0;                            // folded memset
    int v = (tid < NBK) ? bcnt[tid] : 0;
    sd[tid] = v; __syncthreads();
    for (int off = 1; off < 256; off <<= 1) {
        int t = (tid >= off) ? sd[tid - off] : 0;
        __syncthreads();
        sd[tid] += t;
        __syncthreads();
    }
    if (tid < NBK) boff[tid] = sd[tid] - v;   // exclusive
    if (tid == 0) boff[NBK] = E;
}

// tile-local LDS counting sort; T entry = (dloc<<18) | src  (4 B/edge)
#define BTILE 4096
__global__ __launch_bounds__(256) void k_bucket(const int* __restrict__ src,
                                                const int* __restrict__ dst, int E, int N,
                                                const int* __restrict__ boff,
                                                int* __restrict__ bcur,
                                                int* __restrict__ T, int NBK) {
    __shared__ int cnt[256], cnt2[256], lofs[256], gbase[256], boffs[256], sd[256];
    __shared__ int2 staged[BTILE];
    const int tid = threadIdx.x;
    const int tb = blockIdx.x * BTILE;
    const int tn = min(BTILE, E - tb);
    cnt[tid] = 0; cnt2[tid] = 0;
    boffs[tid] = (tid < NBK) ? boff[tid] : 0;
    __syncthreads();
    for (int i = tid; i < tn; i += 256) {
        int d = dst[tb + i];
        d = d < 0 ? 0 : (d >= N ? N - 1 : d);
        atomicAdd(&cnt[d >> 10], 1);
    }
    __syncthreads();
    int v = cnt[tid];
    sd[tid] = v; __syncthreads();
    for (int off = 1; off < 256; off <<= 1) {
        int t = (tid >= off) ? sd[tid - off] : 0;
        __syncthreads();
        sd[tid] += t;
        __syncthreads();
    }
    lofs[tid] = sd[tid] - v;
    if (v > 0 && tid < NBK) gbase[tid] = atomicAdd(&bcur[tid], v);
    __syncthreads();
    for (int i = tid; i < tn; i += 256) {
        int d = dst[tb + i];
        d = d < 0 ? 0 : (d >= N ? N - 1 : d);
        int s = src[tb + i];
        s = s < 0 ? 0 : (s >= N ? N - 1 : s);
        int b = d >> 10;
        int r = atomicAdd(&cnt2[b], 1);
        staged[lofs[b] + r] = make_int2(s, d);
    }
    __syncthreads();
    for (int i = tid; i < tn; i += 256) {
        int2 p = staged[i];
        int b = p.y >> 10;
        T[(size_t)boffs[b] + gbase[b] + (i - lofs[b])] = ((p.y & 1023) << 18) | p.x;
    }
}

// per bucket: LDS degree histogram + 1024-wide scan -> rowptr, then LDS-cursor
// fill of adj (packed T: dloc = p>>18, src = p & 0x3FFFF)
__global__ __launch_bounds__(1024) void k_csr(const int* __restrict__ T,
                                              const int* __restrict__ boff,
                                              int* __restrict__ rowptr,
                                              int* __restrict__ adj, int N, int E) {
    __shared__ int hist[1024];
    __shared__ int sc[1024];
    const int tid = threadIdx.x;
    const int b = blockIdx.x;
    const int node0 = b << 10;
    hist[tid] = 0;
    __syncthreads();
    const int beg = boff[b], end = boff[b + 1];
    for (int i = beg + tid; i < end; i += 1024)
        atomicAdd(&hist[((unsigned)T[i]) >> 18], 1);
    __syncthreads();
    int v = hist[tid];
    sc[tid] = v;
    __syncthreads();
    for (int off = 1; off < 1024; off <<= 1) {
        int t = (tid >= off) ? sc[tid - off] : 0;
        __syncthreads();
        sc[tid] += t;
        __syncthreads();
    }
    const int excl = beg + sc[tid] - v;
    const int n = node0 + tid;
    if (n < N) rowptr[n] = excl;
    if (b == 0 && tid == 0) rowptr[N] = E;
    hist[tid] = excl;
    __syncthreads();
    for (int i = beg + tid; i < end; i += 1024) {
        unsigned p = (unsigned)T[i];
        int pos = atomicAdd(&hist[p >> 18], 1);
        adj[pos] = (int)(p & 0x3FFFFu);
    }
}

// ---------------- MFMA fused projection ----------------
template<int DIN, int DOUT>
__global__ __launch_bounds__(256) void proj_mfma(const float* __restrict__ H,
                                                 const float* __restrict__ Wl,
                                                 const float* __restrict__ Wr,
                                                 const float* __restrict__ bias,
                                                 unsigned short* __restrict__ Pl,
                                                 float* __restrict__ R, int N) {
    constexpr int SP = DIN + 8;
    constexpr int COLT = DOUT / 16;
    __shared__ __bf16 lwl[DOUT * SP];
    __shared__ __bf16 lwrh[DOUT * SP];
    __shared__ __bf16 lwrl[DOUT * SP];
    for (int idx = threadIdx.x; idx < DIN * DOUT; idx += 256) {
        int c = idx / DIN, k = idx % DIN;
        float wl = Wl[idx], wr = Wr[idx];
        __bf16 wrh = (__bf16)wr;
        lwl[c * SP + k] = (__bf16)wl;
        lwrh[c * SP + k] = wrh;
        lwrl[c * SP + k] = (__bf16)(wr - (float)wrh);
    }
    __syncthreads();
    const int wave = threadIdx.x >> 6, lane = threadIdx.x & 63;
    const int quad = lane >> 4, l16 = lane & 15;
    const int n0 = (blockIdx.x * 4 + wave) * 16;
    int arow = n0 + l16;
    if (arow >= N) arow = N - 1;
    const float* hrow = H + (size_t)arow * DIN;

    f32x4 zero = {0.f, 0.f, 0.f, 0.f};
    f32x4 accP[COLT], accR[COLT];
    #pragma unroll
    for (int t = 0; t < COLT; ++t) { accP[t] = zero; accR[t] = zero; }

    for (int k0 = 0; k0 < DIN; k0 += 32) {
        const float* hp = hrow + k0 + quad * 8;
        float4 h0 = *(const float4*)hp;
        float4 h1 = *(const float4*)(hp + 4);
        float hv[8] = {h0.x, h0.y, h0.z, h0.w, h1.x, h1.y, h1.z, h1.w};
        bf16x8 ahi, alo;
        #pragma unroll
        for (int j = 0; j < 8; ++j) {
            __bf16 hb = (__bf16)hv[j];
            ahi[j] = hb;
            alo[j] = (__bf16)(hv[j] - (float)hb);
        }
        const int kk = k0 + quad * 8;
        #pragma unroll
        for (int t = 0; t < COLT; ++t) {
            const int c = t * 16 + l16;
            bf16x8 bl  = *(const bf16x8*)&lwl [c * SP + kk];
            bf16x8 brh = *(const bf16x8*)&lwrh[c * SP + kk];
            bf16x8 brl = *(const bf16x8*)&lwrl[c * SP + kk];
            accP[t] = __builtin_amdgcn_mfma_f32_16x16x32_bf16(ahi, bl,  accP[t], 0, 0, 0);
            accR[t] = __builtin_amdgcn_mfma_f32_16x16x32_bf16(ahi, brh, accR[t], 0, 0, 0);
            accR[t] = __builtin_amdgcn_mfma_f32_16x16x32_bf16(ahi, brl, accR[t], 0, 0, 0);
            accR[t] = __builtin_amdgcn_mfma_f32_16x16x32_bf16(alo, brh, accR[t], 0, 0, 0);
        }
    }
    // C/D layout: col = lane&15, row = quad*4 + reg  [m89-verified]
    #pragma unroll
    for (int t = 0; t < COLT; ++t) {
        const int c = t * 16 + l16;
        const float bc = bias[c];
        #pragma unroll
        for (int r = 0; r < 4; ++r) {
            int node = n0 + quad * 4 + r;
            if (node < N) {
                Pl[(size_t)node * DOUT + c] = f2bf_rne(accP[t][r]);
                R[(size_t)node * DOUT + c] = accR[t][r] + bc;
            }
        }
    }
}

// ---------------- gather: Hout = relu( mean P[j] + Hout ), P bf16, 8 B/lane ----

template<int DOUT> struct GatherCfg {
    static constexpr int L   = DOUT / 4;   // uint2s (4 bf16) per node row
    static constexpr int S   = 64 / L;     // nodes concurrently per wave
    static constexpr int M   = 4;          // sequential nodes per subgroup
    static constexpr int NPW = S * M;
    static constexpr int NPB = NPW * 4;    // 4 waves/block
};

template<int DOUT, bool HEAD>
__global__ __launch_bounds__(256, 6) void gather_kernel(const unsigned short* __restrict__ P,
                                                        const int* __restrict__ rowptr,
                                                        const int* __restrict__ adj,
                                                        float* __restrict__ Hout, int N,
                                                        const float* __restrict__ Wreg,
                                                        const float* __restrict__ breg,
                                                        const float* __restrict__ Wcls,
                                                        const float* __restrict__ bcls,
                                                        float* __restrict__ out) {
    using C = GatherCfg<DOUT>;
    constexpr int L = C::L, S = C::S, M = C::M;
    constexpr int NPW = C::NPW, NPB = C::NPB;
    const int wave = threadIdx.x >> 6, lane = threadIdx.x & 63;
    const int sub = lane / L, cl = lane % L;
    const uint2* __restrict__ P2 = (const uint2*)P;
    float4* __restrict__ H4 = (float4*)Hout;
    const int base = blockIdx.x * NPB + wave * NPW + sub;
    #pragma unroll 1
    for (int m = 0; m < M; ++m) {
        int n = base + m * S;
        if (n >= N) continue;
        int beg = rowptr[n], end = rowptr[n + 1];
        float4 a0 = {0, 0, 0, 0}, a1 = {0, 0, 0, 0}, a2 = {0, 0, 0, 0}, a3 = {0, 0, 0, 0};
        int j = beg;
        while (j < end && (j & 3)) { bfacc(a0, P2[(size_t)adj[j] * L + cl]); ++j; }
        // 16 edges in flight: 4x int4 adj + 16 uint2 P loads per iteration
        for (; j + 16 <= end; j += 16) {
            int4 sA = *(const int4*)(adj + j);
            int4 sB = *(const int4*)(adj + j + 4);
            int4 sC = *(const int4*)(adj + j + 8);
            int4 sD = *(const int4*)(adj + j + 12);
            uint2 p0  = P2[(size_t)sA.x * L + cl];
            uint2 p1  = P2[(size_t)sA.y * L + cl];
            uint2 p2  = P2[(size_t)sA.z * L + cl];
            uint2 p3  = P2[(size_t)sA.w * L + cl];
            uint2 p4  = P2[(size_t)sB.x * L + cl];
            uint2 p5  = P2[(size_t)sB.y * L + cl];
            uint2 p6  = P2[(size_t)sB.z * L + cl];
            uint2 p7  = P2[(size_t)sB.w * L + cl];
            uint2 p8  = P2[(size_t)sC.x * L + cl];
            uint2 p9  = P2[(size_t)sC.y * L + cl];
            uint2 p10 = P2[(size_t)sC.z * L + cl];
            uint2 p11 = P2[(size_t)sC.w * L + cl];
            uint2 p12 = P2[(size_t)sD.x * L + cl];
            uint2 p13 = P2[(size_t)sD.y * L + cl];
            uint2 p14 = P2[(size_t)sD.z * L + cl];
            uint2 p15 = P2[(size_t)sD.w * L + cl];
            bfacc(a0, p0);  bfacc(a1, p1);  bfacc(a2, p2);  bfacc(a3, p3);
            bfacc(a0, p4);  bfacc(a1, p5);  bfacc(a2, p6);  bfacc(a3, p7);
            bfacc(a0, p8);  bfacc(a1, p9);  bfacc(a2, p10); bfacc(a3, p11);
            bfacc(a0, p12); bfacc(a1, p13); bfacc(a2, p14); bfacc(a3, p15);
        }
        if (j + 8 <= end) {
            int4 sA = *(const int4*)(adj + j);
            int4 sB = *(const int4*)(adj + j + 4);
            uint2 p0 = P2[(size_t)sA.x * L + cl];
            uint2 p1 = P2[(size_t)sA.y * L + cl];
            uint2 p2 = P2[(size_t)sA.z * L + cl];
            uint2 p3 = P2[(size_t)sA.w * L + cl];
            uint2 p4 = P2[(size_t)sB.x * L + cl];
            uint2 p5 = P2[(size_t)sB.y * L + cl];
            uint2 p6 = P2[(size_t)sB.z * L + cl];
            uint2 p7 = P2[(size_t)sB.w * L + cl];
            bfacc(a0, p0); bfacc(a1, p1); bfacc(a2, p2); bfacc(a3, p3);
            bfacc(a0, p4); bfacc(a1, p5); bfacc(a2, p6); bfacc(a3, p7);
            j += 8;
        }
        if (j + 4 <= end) {
            int4 sA = *(const int4*)(adj + j);
            bfacc(a0, P2[(size_t)sA.x * L + cl]);
            bfacc(a1, P2[(size_t)sA.y * L + cl]);
            bfacc(a2, P2[(size_t)sA.z * L + cl]);
            bfacc(a3, P2[(size_t)sA.w * L + cl]);
            j += 4;
        }
        for (; j < end; ++j) bfacc(a0, P2[(size_t)adj[j] * L + cl]);
        int deg = end - beg;
        float inv = deg > 0 ? 1.0f / (float)deg : 0.0f;
        float4 r = H4[(size_t)n * L + cl];
        float4 o;
        o.x = fmaxf((a0.x + a1.x + a2.x + a3.x) * inv + r.x, 0.0f);
        o.y = fmaxf((a0.y + a1.y + a2.y + a3.y) * inv + r.y, 0.0f);
        o.z = fmaxf((a0.z + a1.z + a2.z + a3.z) * inv + r.z, 0.0f);
        o.w = fmaxf((a0.w + a1.w + a2.w + a3.w) * inv + r.w, 0.0f);
        if constexpr (HEAD) {
            // fused linear heads: per-lane partial dot (4 of 16 features),
            // 2-step shfl reduce across the 4-lane subgroup
            float4 wr = ((const float4*)Wreg)[cl];
            float4 wc = ((const float4*)Wcls)[cl];
            float pr = o.x * wr.x + o.y * wr.y + o.z * wr.z + o.w * wr.w;
            float pc = o.x * wc.x + o.y * wc.y + o.z * wc.z + o.w * wc.w;
            pr += __shfl_xor(pr, 1); pr += __shfl_xor(pr, 2);
            pc += __shfl_xor(pc, 1); pc += __shfl_xor(pc, 2);
            if (cl == 0) {
                out[n] = pr + breg[0];
                out[(size_t)N + n] = pc + bcls[0];
            }
        } else {
            H4[(size_t)n * L + cl] = o;
        }
    }
}

extern "C" void kernel_launch(void* const* d_in, const int* in_sizes, int n_in,
                              void* d_out, int out_size, void* d_ws, size_t ws_size,
                              hipStream_t stream) {
    const float* x    = (const float*)d_in[0];
    const int*   ei   = (const int*)d_in[1];
    const float* W1l  = (const float*)d_in[2];
    const float* b1l  = (const float*)d_in[3];
    const float* W1r  = (const float*)d_in[4];
    const float* W2l  = (const float*)d_in[5];
    const float* b2l  = (const float*)d_in[6];
    const float* W2r  = (const float*)d_in[7];
    const float* W3l  = (const float*)d_in[8];
    const float* b3l  = (const float*)d_in[9];
    const float* W3r  = (const float*)d_in[10];
    const float* Wreg = (const float*)d_in[11];
    const float* breg = (const float*)d_in[12];
    const float* Wcls = (const float*)d_in[13];
    const float* bcls = (const float*)d_in[14];

    const int N = in_sizes[0] / 128;
    const int E = in_sizes[1] / 2;
    const int* src = ei;
    const int* dst = ei + E;

    char* ws = (char*)d_ws;
    size_t off = 0;
    auto alloc = [&](size_t bytes) -> void* {
        void* p = ws + off;
        off += (bytes + 255) & ~(size_t)255;
        return p;
    };
    int*   rowptr = (int*)alloc((size_t)(N + 1) * 4);
    int*   bcnt   = (int*)alloc(1024);
    int*   bcur   = (int*)alloc(1024);
    int*   boff   = (int*)alloc(1028);
    int*   adj    = (int*)alloc((size_t)E * 4);
    unsigned short* A = (unsigned short*)alloc((size_t)N * 64 * 2);  // bf16 P
    float* B      = (float*)alloc((size_t)N * 64 * 4);  // h1; doubles as T during CSR build
    float* C      = (float*)alloc((size_t)N * 32 * 4);  // h2
    float* D      = (float*)alloc((size_t)N * 16 * 4);  // h3 residual (R of layer 3)
    int*   T      = (int*)B;                             // packed edges, E*4B <= N*64*4B

    const int NBK = (N + 1023) >> 10;     // buckets (196; must be <= 256)

    // ---- CSR build ----
    hipMemsetAsync(bcnt, 0, 1024, stream);
    k_bcount<<<1024, 256, 0, stream>>>(dst, E, N, bcnt);
    k_bscan<<<1, 256, 0, stream>>>(bcnt, boff, bcur, NBK, E);
    k_bucket<<<(E + BTILE - 1) / BTILE, 256, 0, stream>>>(src, dst, E, N, boff, bcur, T, NBK);
    k_csr<<<NBK, 1024, 0, stream>>>(T, boff, rowptr, adj, N, E);

    const int PB = 64;   // nodes per proj_mfma block (4 waves x 16)
    constexpr int G64 = GatherCfg<64>::NPB;
    constexpr int G32 = GatherCfg<32>::NPB;
    constexpr int G16 = GatherCfg<16>::NPB;

    // ---- layer 1: 128 -> 64 ----
    proj_mfma<128, 64><<<(N + PB - 1) / PB, 256, 0, stream>>>(x, W1l, W1r, b1l, A, B, N);
    gather_kernel<64, false><<<(N + G64 - 1) / G64, 256, 0, stream>>>(
        A, rowptr, adj, B, N, nullptr, nullptr, nullptr, nullptr, nullptr);
    // ---- layer 2: 64 -> 32 ----
    proj_mfma<64, 32><<<(N + PB - 1) / PB, 256, 0, stream>>>(B, W2l, W2r, b2l, A, C, N);
    gather_kernel<32, false><<<(N + G32 - 1) / G32, 256, 0, stream>>>(
        A, rowptr, adj, C, N, nullptr, nullptr, nullptr, nullptr, nullptr);
    // ---- layer 3: 32 -> 16, heads fused into the gather ----
    proj_mfma<32, 16><<<(N + PB - 1) / PB, 256, 0, stream>>>(C, W3l, W3r, b3l, A, D, N);
    gather_kernel<16, true><<<(N + G16 - 1) / G16, 256, 0, stream>>>(
        A, rowptr, adj, D, N, Wreg, breg, Wcls, bcls, (float*)d_out);
}

// Round 3
// 772.253 us; speedup vs baseline: 1.0006x; 1.0006x over previous
//
#include <hip/hip_runtime.h>

// ---------------------------------------------------------------------------
// BikeSafetyGNN: 3-layer GraphSAGE (mean) + 2 linear heads, fp32.
// R12: compile-fix of R11 — __builtin_nontemporal_* requires native clang
//      ext_vector_type pointers, not HIP_vector_type (int4/float4 classes).
//      Same content as R11: R9 8-deep gather loop + head fusion + NT hints
//      on zero-reuse streams (rowptr, adj, H residual read, H store).
// R9: uint2 gather shape (16 lanes x 8 B = full 128 B row/node), T packed
//     to 4 B/edge, bcur zeroing folded into k_bscan.
// ---------------------------------------------------------------------------

typedef __bf16 bf16x8 __attribute__((ext_vector_type(8)));
typedef float  f32x4  __attribute__((ext_vector_type(4)));
typedef int    i32x4  __attribute__((ext_vector_type(4)));

__device__ __forceinline__ unsigned short f2bf_rne(float f) {
    unsigned int u = __float_as_uint(f);
    u = (u + 0x7FFFu + ((u >> 16) & 1u)) >> 16;
    return (unsigned short)u;
}

// unpack 4 bf16 (packed little-endian in uint2) and accumulate into float4
__device__ __forceinline__ void bfacc(float4& a, const uint2 q) {
    a.x += __uint_as_float(q.x << 16);
    a.y += __uint_as_float(q.x & 0xFFFF0000u);
    a.z += __uint_as_float(q.y << 16);
    a.w += __uint_as_float(q.y & 0xFFFF0000u);
}

// ---------------- CSR build (bucket = dst >> 10) ----------------

__global__ __launch_bounds__(256) void k_bcount(const int* __restrict__ dst, int E, int N,
                                                int* __restrict__ bcnt) {
    __shared__ int h[256];
    const int tid = threadIdx.x;
    h[tid] = 0;
    __syncthreads();
    const int stride = gridDim.x * 256;
    for (int i = blockIdx.x * 256 + tid; i < E; i += stride) {
        int d = dst[i];
        d = d < 0 ? 0 : (d >= N ? N - 1 : d);
        atomicAdd(&h[d >> 10], 1);
    }
    __syncthreads();
    if (h[tid]) atomicAdd(&bcnt[tid], h[tid]);
}

__global__ __launch_bounds__(256) void k_bscan(const int* __restrict__ bcnt,
                                               int* __restrict__ boff,
                                               int* __restrict__ bcur, int NBK, int E) {
    __shared__ int sd[256];
    const int tid = threadIdx.x;
    bcur[tid] = 0;                            // folded memset
    int v = (tid < NBK) ? bcnt[tid] : 0;
    sd[tid] = v; __syncthreads();
    for (int off = 1; off < 256; off <<= 1) {
        int t = (tid >= off) ? sd[tid - off] : 0;
        __syncthreads();
        sd[tid] += t;
        __syncthreads();
    }
    if (tid < NBK) boff[tid] = sd[tid] - v;   // exclusive
    if (tid == 0) boff[NBK] = E;
}

// tile-local LDS counting sort; T entry = (dloc<<18) | src  (4 B/edge)
#define BTILE 4096
__global__ __launch_bounds__(256) void k_bucket(const int* __restrict__ src,
                                                const int* __restrict__ dst, int E, int N,
                                                const int* __restrict__ boff,
                                                int* __restrict__ bcur,
                                                int* __restrict__ T, int NBK) {
    __shared__ int cnt[256], cnt2[256], lofs[256], gbase[256], boffs[256], sd[256];
    __shared__ int2 staged[BTILE];
    const int tid = threadIdx.x;
    const int tb = blockIdx.x * BTILE;
    const int tn = min(BTILE, E - tb);
    cnt[tid] = 0; cnt2[tid] = 0;
    boffs[tid] = (tid < NBK) ? boff[tid] : 0;
    __syncthreads();
    for (int i = tid; i < tn; i += 256) {
        int d = dst[tb + i];
        d = d < 0 ? 0 : (d >= N ? N - 1 : d);
        atomicAdd(&cnt[d >> 10], 1);
    }
    __syncthreads();
    int v = cnt[tid];
    sd[tid] = v; __syncthreads();
    for (int off = 1; off < 256; off <<= 1) {
        int t = (tid >= off) ? sd[tid - off] : 0;
        __syncthreads();
        sd[tid] += t;
        __syncthreads();
    }
    lofs[tid] = sd[tid] - v;
    if (v > 0 && tid < NBK) gbase[tid] = atomicAdd(&bcur[tid], v);
    __syncthreads();
    for (int i = tid; i < tn; i += 256) {
        int d = dst[tb + i];
        d = d < 0 ? 0 : (d >= N ? N - 1 : d);
        int s = src[tb + i];
        s = s < 0 ? 0 : (s >= N ? N - 1 : s);
        int b = d >> 10;
        int r = atomicAdd(&cnt2[b], 1);
        staged[lofs[b] + r] = make_int2(s, d);
    }
    __syncthreads();
    for (int i = tid; i < tn; i += 256) {
        int2 p = staged[i];
        int b = p.y >> 10;
        T[(size_t)boffs[b] + gbase[b] + (i - lofs[b])] = ((p.y & 1023) << 18) | p.x;
    }
}

// per bucket: LDS degree histogram + 1024-wide scan -> rowptr, then LDS-cursor
// fill of adj (packed T: dloc = p>>18, src = p & 0x3FFFF)
__global__ __launch_bounds__(1024) void k_csr(const int* __restrict__ T,
                                              const int* __restrict__ boff,
                                              int* __restrict__ rowptr,
                                              int* __restrict__ adj, int N, int E) {
    __shared__ int hist[1024];
    __shared__ int sc[1024];
    const int tid = threadIdx.x;
    const int b = blockIdx.x;
    const int node0 = b << 10;
    hist[tid] = 0;
    __syncthreads();
    const int beg = boff[b], end = boff[b + 1];
    for (int i = beg + tid; i < end; i += 1024)
        atomicAdd(&hist[((unsigned)T[i]) >> 18], 1);
    __syncthreads();
    int v = hist[tid];
    sc[tid] = v;
    __syncthreads();
    for (int off = 1; off < 1024; off <<= 1) {
        int t = (tid >= off) ? sc[tid - off] : 0;
        __syncthreads();
        sc[tid] += t;
        __syncthreads();
    }
    const int excl = beg + sc[tid] - v;
    const int n = node0 + tid;
    if (n < N) rowptr[n] = excl;
    if (b == 0 && tid == 0) rowptr[N] = E;
    hist[tid] = excl;
    __syncthreads();
    for (int i = beg + tid; i < end; i += 1024) {
        unsigned p = (unsigned)T[i];
        int pos = atomicAdd(&hist[p >> 18], 1);
        adj[pos] = (int)(p & 0x3FFFFu);
    }
}

// ---------------- MFMA fused projection ----------------
template<int DIN, int DOUT>
__global__ __launch_bounds__(256) void proj_mfma(const float* __restrict__ H,
                                                 const float* __restrict__ Wl,
                                                 const float* __restrict__ Wr,
                                                 const float* __restrict__ bias,
                                                 unsigned short* __restrict__ Pl,
                                                 float* __restrict__ R, int N) {
    constexpr int SP = DIN + 8;
    constexpr int COLT = DOUT / 16;
    __shared__ __bf16 lwl[DOUT * SP];
    __shared__ __bf16 lwrh[DOUT * SP];
    __shared__ __bf16 lwrl[DOUT * SP];
    for (int idx = threadIdx.x; idx < DIN * DOUT; idx += 256) {
        int c = idx / DIN, k = idx % DIN;
        float wl = Wl[idx], wr = Wr[idx];
        __bf16 wrh = (__bf16)wr;
        lwl[c * SP + k] = (__bf16)wl;
        lwrh[c * SP + k] = wrh;
        lwrl[c * SP + k] = (__bf16)(wr - (float)wrh);
    }
    __syncthreads();
    const int wave = threadIdx.x >> 6, lane = threadIdx.x & 63;
    const int quad = lane >> 4, l16 = lane & 15;
    const int n0 = (blockIdx.x * 4 + wave) * 16;
    int arow = n0 + l16;
    if (arow >= N) arow = N - 1;
    const float* hrow = H + (size_t)arow * DIN;

    f32x4 zero = {0.f, 0.f, 0.f, 0.f};
    f32x4 accP[COLT], accR[COLT];
    #pragma unroll
    for (int t = 0; t < COLT; ++t) { accP[t] = zero; accR[t] = zero; }

    for (int k0 = 0; k0 < DIN; k0 += 32) {
        const float* hp = hrow + k0 + quad * 8;
        float4 h0 = *(const float4*)hp;
        float4 h1 = *(const float4*)(hp + 4);
        float hv[8] = {h0.x, h0.y, h0.z, h0.w, h1.x, h1.y, h1.z, h1.w};
        bf16x8 ahi, alo;
        #pragma unroll
        for (int j = 0; j < 8; ++j) {
            __bf16 hb = (__bf16)hv[j];
            ahi[j] = hb;
            alo[j] = (__bf16)(hv[j] - (float)hb);
        }
        const int kk = k0 + quad * 8;
        #pragma unroll
        for (int t = 0; t < COLT; ++t) {
            const int c = t * 16 + l16;
            bf16x8 bl  = *(const bf16x8*)&lwl [c * SP + kk];
            bf16x8 brh = *(const bf16x8*)&lwrh[c * SP + kk];
            bf16x8 brl = *(const bf16x8*)&lwrl[c * SP + kk];
            accP[t] = __builtin_amdgcn_mfma_f32_16x16x32_bf16(ahi, bl,  accP[t], 0, 0, 0);
            accR[t] = __builtin_amdgcn_mfma_f32_16x16x32_bf16(ahi, brh, accR[t], 0, 0, 0);
            accR[t] = __builtin_amdgcn_mfma_f32_16x16x32_bf16(ahi, brl, accR[t], 0, 0, 0);
            accR[t] = __builtin_amdgcn_mfma_f32_16x16x32_bf16(alo, brh, accR[t], 0, 0, 0);
        }
    }
    // C/D layout: col = lane&15, row = quad*4 + reg  [m89-verified]
    #pragma unroll
    for (int t = 0; t < COLT; ++t) {
        const int c = t * 16 + l16;
        const float bc = bias[c];
        #pragma unroll
        for (int r = 0; r < 4; ++r) {
            int node = n0 + quad * 4 + r;
            if (node < N) {
                Pl[(size_t)node * DOUT + c] = f2bf_rne(accP[t][r]);
                R[(size_t)node * DOUT + c] = accR[t][r] + bc;
            }
        }
    }
}

// ---------------- gather: Hout = relu( mean P[j] + Hout ), P bf16, 8 B/lane ----

template<int DOUT> struct GatherCfg {
    static constexpr int L   = DOUT / 4;   // uint2s (4 bf16) per node row
    static constexpr int S   = 64 / L;     // nodes concurrently per wave
    static constexpr int M   = 4;          // sequential nodes per subgroup
    static constexpr int NPW = S * M;
    static constexpr int NPB = NPW * 4;    // 4 waves/block
};

template<int DOUT, bool HEAD>
__global__ __launch_bounds__(256, 6) void gather_kernel(const unsigned short* __restrict__ P,
                                                        const int* __restrict__ rowptr,
                                                        const int* __restrict__ adj,
                                                        float* __restrict__ Hout, int N,
                                                        const float* __restrict__ Wreg,
                                                        const float* __restrict__ breg,
                                                        const float* __restrict__ Wcls,
                                                        const float* __restrict__ bcls,
                                                        float* __restrict__ out) {
    using C = GatherCfg<DOUT>;
    constexpr int L = C::L, S = C::S, M = C::M;
    constexpr int NPW = C::NPW, NPB = C::NPB;
    const int wave = threadIdx.x >> 6, lane = threadIdx.x & 63;
    const int sub = lane / L, cl = lane % L;
    const uint2* __restrict__ P2 = (const uint2*)P;
    f32x4* __restrict__ H4 = (f32x4*)Hout;
    const int base = blockIdx.x * NPB + wave * NPW + sub;
    #pragma unroll 1
    for (int m = 0; m < M; ++m) {
        int n = base + m * S;
        if (n >= N) continue;
        int beg = __builtin_nontemporal_load(rowptr + n);
        int end = __builtin_nontemporal_load(rowptr + n + 1);
        float4 a0 = {0, 0, 0, 0}, a1 = {0, 0, 0, 0}, a2 = {0, 0, 0, 0}, a3 = {0, 0, 0, 0};
        int j = beg;
        while (j < end && (j & 3)) { bfacc(a0, P2[(size_t)adj[j] * L + cl]); ++j; }
        for (; j + 8 <= end; j += 8) {
            i32x4 sA = __builtin_nontemporal_load((const i32x4*)(adj + j));
            i32x4 sB = __builtin_nontemporal_load((const i32x4*)(adj + j + 4));
            uint2 p0 = P2[(size_t)sA.x * L + cl];
            uint2 p1 = P2[(size_t)sA.y * L + cl];
            uint2 p2 = P2[(size_t)sA.z * L + cl];
            uint2 p3 = P2[(size_t)sA.w * L + cl];
            uint2 p4 = P2[(size_t)sB.x * L + cl];
            uint2 p5 = P2[(size_t)sB.y * L + cl];
            uint2 p6 = P2[(size_t)sB.z * L + cl];
            uint2 p7 = P2[(size_t)sB.w * L + cl];
            bfacc(a0, p0); bfacc(a1, p1); bfacc(a2, p2); bfacc(a3, p3);
            bfacc(a0, p4); bfacc(a1, p5); bfacc(a2, p6); bfacc(a3, p7);
        }
        if (j + 4 <= end) {
            i32x4 sA = __builtin_nontemporal_load((const i32x4*)(adj + j));
            bfacc(a0, P2[(size_t)sA.x * L + cl]);
            bfacc(a1, P2[(size_t)sA.y * L + cl]);
            bfacc(a2, P2[(size_t)sA.z * L + cl]);
            bfacc(a3, P2[(size_t)sA.w * L + cl]);
            j += 4;
        }
        for (; j < end; ++j) bfacc(a0, P2[(size_t)adj[j] * L + cl]);
        int deg = end - beg;
        float inv = deg > 0 ? 1.0f / (float)deg : 0.0f;
        f32x4 r = __builtin_nontemporal_load(&H4[(size_t)n * L + cl]);
        f32x4 o;
        o.x = fmaxf((a0.x + a1.x + a2.x + a3.x) * inv + r.x, 0.0f);
        o.y = fmaxf((a0.y + a1.y + a2.y + a3.y) * inv + r.y, 0.0f);
        o.z = fmaxf((a0.z + a1.z + a2.z + a3.z) * inv + r.z, 0.0f);
        o.w = fmaxf((a0.w + a1.w + a2.w + a3.w) * inv + r.w, 0.0f);
        if constexpr (HEAD) {
            // fused linear heads: per-lane partial dot (4 of 16 features),
            // 2-step shfl reduce across the 4-lane subgroup
            float4 wr = ((const float4*)Wreg)[cl];
            float4 wc = ((const float4*)Wcls)[cl];
            float pr = o.x * wr.x + o.y * wr.y + o.z * wr.z + o.w * wr.w;
            float pc = o.x * wc.x + o.y * wc.y + o.z * wc.z + o.w * wc.w;
            pr += __shfl_xor(pr, 1); pr += __shfl_xor(pr, 2);
            pc += __shfl_xor(pc, 1); pc += __shfl_xor(pc, 2);
            if (cl == 0) {
                out[n] = pr + breg[0];
                out[(size_t)N + n] = pc + bcls[0];
            }
        } else {
            __builtin_nontemporal_store(o, &H4[(size_t)n * L + cl]);
        }
    }
}

extern "C" void kernel_launch(void* const* d_in, const int* in_sizes, int n_in,
                              void* d_out, int out_size, void* d_ws, size_t ws_size,
                              hipStream_t stream) {
    const float* x    = (const float*)d_in[0];
    const int*   ei   = (const int*)d_in[1];
    const float* W1l  = (const float*)d_in[2];
    const float* b1l  = (const float*)d_in[3];
    const float* W1r  = (const float*)d_in[4];
    const float* W2l  = (const float*)d_in[5];
    const float* b2l  = (const float*)d_in[6];
    const float* W2r  = (const float*)d_in[7];
    const float* W3l  = (const float*)d_in[8];
    const float* b3l  = (const float*)d_in[9];
    const float* W3r  = (const float*)d_in[10];
    const float* Wreg = (const float*)d_in[11];
    const float* breg = (const float*)d_in[12];
    const float* Wcls = (const float*)d_in[13];
    const float* bcls = (const float*)d_in[14];

    const int N = in_sizes[0] / 128;
    const int E = in_sizes[1] / 2;
    const int* src = ei;
    const int* dst = ei + E;

    char* ws = (char*)d_ws;
    size_t off = 0;
    auto alloc = [&](size_t bytes) -> void* {
        void* p = ws + off;
        off += (bytes + 255) & ~(size_t)255;
        return p;
    };
    int*   rowptr = (int*)alloc((size_t)(N + 1) * 4);
    int*   bcnt   = (int*)alloc(1024);
    int*   bcur   = (int*)alloc(1024);
    int*   boff   = (int*)alloc(1028);
    int*   adj    = (int*)alloc((size_t)E * 4);
    unsigned short* A = (unsigned short*)alloc((size_t)N * 64 * 2);  // bf16 P
    float* B      = (float*)alloc((size_t)N * 64 * 4);  // h1; doubles as T during CSR build
    float* C      = (float*)alloc((size_t)N * 32 * 4);  // h2
    float* D      = (float*)alloc((size_t)N * 16 * 4);  // h3 residual (R of layer 3)
    int*   T      = (int*)B;                             // packed edges, E*4B <= N*64*4B

    const int NBK = (N + 1023) >> 10;     // buckets (196; must be <= 256)

    // ---- CSR build ----
    hipMemsetAsync(bcnt, 0, 1024, stream);
    k_bcount<<<1024, 256, 0, stream>>>(dst, E, N, bcnt);
    k_bscan<<<1, 256, 0, stream>>>(bcnt, boff, bcur, NBK, E);
    k_bucket<<<(E + BTILE - 1) / BTILE, 256, 0, stream>>>(src, dst, E, N, boff, bcur, T, NBK);
    k_csr<<<NBK, 1024, 0, stream>>>(T, boff, rowptr, adj, N, E);

    const int PB = 64;   // nodes per proj_mfma block (4 waves x 16)
    constexpr int G64 = GatherCfg<64>::NPB;
    constexpr int G32 = GatherCfg<32>::NPB;
    constexpr int G16 = GatherCfg<16>::NPB;

    // ---- layer 1: 128 -> 64 ----
    proj_mfma<128, 64><<<(N + PB - 1) / PB, 256, 0, stream>>>(x, W1l, W1r, b1l, A, B, N);
    gather_kernel<64, false><<<(N + G64 - 1) / G64, 256, 0, stream>>>(
        A, rowptr, adj, B, N, nullptr, nullptr, nullptr, nullptr, nullptr);
    // ---- layer 2: 64 -> 32 ----
    proj_mfma<64, 32><<<(N + PB - 1) / PB, 256, 0, stream>>>(B, W2l, W2r, b2l, A, C, N);
    gather_kernel<32, false><<<(N + G32 - 1) / G32, 256, 0, stream>>>(
        A, rowptr, adj, C, N, nullptr, nullptr, nullptr, nullptr, nullptr);
    // ---- layer 3: 32 -> 16, heads fused into the gather ----
    proj_mfma<32, 16><<<(N + PB - 1) / PB, 256, 0, stream>>>(C, W3l, W3r, b3l, A, D, N);
    gather_kernel<16, true><<<(N + G16 - 1) / G16, 256, 0, stream>>>(
        A, rowptr, adj, D, N, Wreg, breg, Wcls, bcls, (float*)d_out);
}

// Round 4
// 708.265 us; speedup vs baseline: 1.0910x; 1.0903x over previous
//
#include <hip/hip_runtime.h>

// ---------------------------------------------------------------------------
// BikeSafetyGNN: 3-layer GraphSAGE (mean) + 2 linear heads, fp32.
// R13: (a) revert R12's nontemporal hints (they RAISED fetch 393->417MB and
//      gather<64> 125.6->144us: rowptr/adj/P lines have real short-term reuse).
//      (b) fuse proj_{l+1} into gather_l: block stages its nodes' h-rows in
//      LDS (17-18KB, still 6 blk/CU), then MFMA-projects them as an epilogue
//      (weights from global, same bf16 hi/lo split -> identical numerics).
//      Kills proj2+proj3 passes and the h1/h2 HBM round-trips (~154MB).
//      Buffers: new A2 (P2) since A1 is still randomly read during g64;
//      A3 aliases A1 (dead after layer 2). Head fusion (R10) kept.
// R9: uint2 gather shape (16 lanes x 8 B = full 128 B row/node), T packed
//     to 4 B/edge, bcur zeroing folded into k_bscan.
// ---------------------------------------------------------------------------

typedef __bf16 bf16x8 __attribute__((ext_vector_type(8)));
typedef float  f32x4  __attribute__((ext_vector_type(4)));

__device__ __forceinline__ unsigned short f2bf_rne(float f) {
    unsigned int u = __float_as_uint(f);
    u = (u + 0x7FFFu + ((u >> 16) & 1u)) >> 16;
    return (unsigned short)u;
}

// unpack 4 bf16 (packed little-endian in uint2) and accumulate into float4
__device__ __forceinline__ void bfacc(float4& a, const uint2 q) {
    a.x += __uint_as_float(q.x << 16);
    a.y += __uint_as_float(q.x & 0xFFFF0000u);
    a.z += __uint_as_float(q.y << 16);
    a.w += __uint_as_float(q.y & 0xFFFF0000u);
}

// ---------------- CSR build (bucket = dst >> 10) ----------------

__global__ __launch_bounds__(256) void k_bcount(const int* __restrict__ dst, int E, int N,
                                                int* __restrict__ bcnt) {
    __shared__ int h[256];
    const int tid = threadIdx.x;
    h[tid] = 0;
    __syncthreads();
    const int stride = gridDim.x * 256;
    for (int i = blockIdx.x * 256 + tid; i < E; i += stride) {
        int d = dst[i];
        d = d < 0 ? 0 : (d >= N ? N - 1 : d);
        atomicAdd(&h[d >> 10], 1);
    }
    __syncthreads();
    if (h[tid]) atomicAdd(&bcnt[tid], h[tid]);
}

__global__ __launch_bounds__(256) void k_bscan(const int* __restrict__ bcnt,
                                               int* __restrict__ boff,
                                               int* __restrict__ bcur, int NBK, int E) {
    __shared__ int sd[256];
    const int tid = threadIdx.x;
    bcur[tid] = 0;                            // folded memset
    int v = (tid < NBK) ? bcnt[tid] : 0;
    sd[tid] = v; __syncthreads();
    for (int off = 1; off < 256; off <<= 1) {
        int t = (tid >= off) ? sd[tid - off] : 0;
        __syncthreads();
        sd[tid] += t;
        __syncthreads();
    }
    if (tid < NBK) boff[tid] = sd[tid] - v;   // exclusive
    if (tid == 0) boff[NBK] = E;
}

// tile-local LDS counting sort; T entry = (dloc<<18) | src  (4 B/edge)
#define BTILE 4096
__global__ __launch_bounds__(256) void k_bucket(const int* __restrict__ src,
                                                const int* __restrict__ dst, int E, int N,
                                                const int* __restrict__ boff,
                                                int* __restrict__ bcur,
                                                int* __restrict__ T, int NBK) {
    __shared__ int cnt[256], cnt2[256], lofs[256], gbase[256], boffs[256], sd[256];
    __shared__ int2 staged[BTILE];
    const int tid = threadIdx.x;
    const int tb = blockIdx.x * BTILE;
    const int tn = min(BTILE, E - tb);
    cnt[tid] = 0; cnt2[tid] = 0;
    boffs[tid] = (tid < NBK) ? boff[tid] : 0;
    __syncthreads();
    for (int i = tid; i < tn; i += 256) {
        int d = dst[tb + i];
        d = d < 0 ? 0 : (d >= N ? N - 1 : d);
        atomicAdd(&cnt[d >> 10], 1);
    }
    __syncthreads();
    int v = cnt[tid];
    sd[tid] = v; __syncthreads();
    for (int off = 1; off < 256; off <<= 1) {
        int t = (tid >= off) ? sd[tid - off] : 0;
        __syncthreads();
        sd[tid] += t;
        __syncthreads();
    }
    lofs[tid] = sd[tid] - v;
    if (v > 0 && tid < NBK) gbase[tid] = atomicAdd(&bcur[tid], v);
    __syncthreads();
    for (int i = tid; i < tn; i += 256) {
        int d = dst[tb + i];
        d = d < 0 ? 0 : (d >= N ? N - 1 : d);
        int s = src[tb + i];
        s = s < 0 ? 0 : (s >= N ? N - 1 : s);
        int b = d >> 10;
        int r = atomicAdd(&cnt2[b], 1);
        staged[lofs[b] + r] = make_int2(s, d);
    }
    __syncthreads();
    for (int i = tid; i < tn; i += 256) {
        int2 p = staged[i];
        int b = p.y >> 10;
        T[(size_t)boffs[b] + gbase[b] + (i - lofs[b])] = ((p.y & 1023) << 18) | p.x;
    }
}

// per bucket: LDS degree histogram + 1024-wide scan -> rowptr, then LDS-cursor
// fill of adj (packed T: dloc = p>>18, src = p & 0x3FFFF)
__global__ __launch_bounds__(1024) void k_csr(const int* __restrict__ T,
                                              const int* __restrict__ boff,
                                              int* __restrict__ rowptr,
                                              int* __restrict__ adj, int N, int E) {
    __shared__ int hist[1024];
    __shared__ int sc[1024];
    const int tid = threadIdx.x;
    const int b = blockIdx.x;
    const int node0 = b << 10;
    hist[tid] = 0;
    __syncthreads();
    const int beg = boff[b], end = boff[b + 1];
    for (int i = beg + tid; i < end; i += 1024)
        atomicAdd(&hist[((unsigned)T[i]) >> 18], 1);
    __syncthreads();
    int v = hist[tid];
    sc[tid] = v;
    __syncthreads();
    for (int off = 1; off < 1024; off <<= 1) {
        int t = (tid >= off) ? sc[tid - off] : 0;
        __syncthreads();
        sc[tid] += t;
        __syncthreads();
    }
    const int excl = beg + sc[tid] - v;
    const int n = node0 + tid;
    if (n < N) rowptr[n] = excl;
    if (b == 0 && tid == 0) rowptr[N] = E;
    hist[tid] = excl;
    __syncthreads();
    for (int i = beg + tid; i < end; i += 1024) {
        unsigned p = (unsigned)T[i];
        int pos = atomicAdd(&hist[p >> 18], 1);
        adj[pos] = (int)(p & 0x3FFFFu);
    }
}

// ---------------- MFMA fused projection (layer 1 only) ----------------
template<int DIN, int DOUT>
__global__ __launch_bounds__(256) void proj_mfma(const float* __restrict__ H,
                                                 const float* __restrict__ Wl,
                                                 const float* __restrict__ Wr,
                                                 const float* __restrict__ bias,
                                                 unsigned short* __restrict__ Pl,
                                                 float* __restrict__ R, int N) {
    constexpr int SP = DIN + 8;
    constexpr int COLT = DOUT / 16;
    __shared__ __bf16 lwl[DOUT * SP];
    __shared__ __bf16 lwrh[DOUT * SP];
    __shared__ __bf16 lwrl[DOUT * SP];
    for (int idx = threadIdx.x; idx < DIN * DOUT; idx += 256) {
        int c = idx / DIN, k = idx % DIN;
        float wl = Wl[idx], wr = Wr[idx];
        __bf16 wrh = (__bf16)wr;
        lwl[c * SP + k] = (__bf16)wl;
        lwrh[c * SP + k] = wrh;
        lwrl[c * SP + k] = (__bf16)(wr - (float)wrh);
    }
    __syncthreads();
    const int wave = threadIdx.x >> 6, lane = threadIdx.x & 63;
    const int quad = lane >> 4, l16 = lane & 15;
    const int n0 = (blockIdx.x * 4 + wave) * 16;
    int arow = n0 + l16;
    if (arow >= N) arow = N - 1;
    const float* hrow = H + (size_t)arow * DIN;

    f32x4 zero = {0.f, 0.f, 0.f, 0.f};
    f32x4 accP[COLT], accR[COLT];
    #pragma unroll
    for (int t = 0; t < COLT; ++t) { accP[t] = zero; accR[t] = zero; }

    for (int k0 = 0; k0 < DIN; k0 += 32) {
        const float* hp = hrow + k0 + quad * 8;
        float4 h0 = *(const float4*)hp;
        float4 h1 = *(const float4*)(hp + 4);
        float hv[8] = {h0.x, h0.y, h0.z, h0.w, h1.x, h1.y, h1.z, h1.w};
        bf16x8 ahi, alo;
        #pragma unroll
        for (int j = 0; j < 8; ++j) {
            __bf16 hb = (__bf16)hv[j];
            ahi[j] = hb;
            alo[j] = (__bf16)(hv[j] - (float)hb);
        }
        const int kk = k0 + quad * 8;
        #pragma unroll
        for (int t = 0; t < COLT; ++t) {
            const int c = t * 16 + l16;
            bf16x8 bl  = *(const bf16x8*)&lwl [c * SP + kk];
            bf16x8 brh = *(const bf16x8*)&lwrh[c * SP + kk];
            bf16x8 brl = *(const bf16x8*)&lwrl[c * SP + kk];
            accP[t] = __builtin_amdgcn_mfma_f32_16x16x32_bf16(ahi, bl,  accP[t], 0, 0, 0);
            accR[t] = __builtin_amdgcn_mfma_f32_16x16x32_bf16(ahi, brh, accR[t], 0, 0, 0);
            accR[t] = __builtin_amdgcn_mfma_f32_16x16x32_bf16(ahi, brl, accR[t], 0, 0, 0);
            accR[t] = __builtin_amdgcn_mfma_f32_16x16x32_bf16(alo, brh, accR[t], 0, 0, 0);
        }
    }
    // C/D layout: col = lane&15, row = quad*4 + reg  [m89-verified]
    #pragma unroll
    for (int t = 0; t < COLT; ++t) {
        const int c = t * 16 + l16;
        const float bc = bias[c];
        #pragma unroll
        for (int r = 0; r < 4; ++r) {
            int node = n0 + quad * 4 + r;
            if (node < N) {
                Pl[(size_t)node * DOUT + c] = f2bf_rne(accP[t][r]);
                R[(size_t)node * DOUT + c] = accR[t][r] + bc;
            }
        }
    }
}

// ---------------- fused gather + next-layer projection ----------------
// gather phase: h[n] = relu( mean_j P[adj] + Rres[n] )   (h staged in LDS)
// proj phase:   Pout[n] = bf16( h W_l^T ),  Rout[n] = h W_r^T + b  (MFMA)
template<int D, int DP>
__global__ __launch_bounds__(256, 6) void gather_proj(const unsigned short* __restrict__ P,
                                                      const int* __restrict__ rowptr,
                                                      const int* __restrict__ adj,
                                                      const float* __restrict__ Rres,
                                                      const float* __restrict__ Wl,
                                                      const float* __restrict__ Wr,
                                                      const float* __restrict__ bias,
                                                      unsigned short* __restrict__ Pout,
                                                      float* __restrict__ Rout, int N) {
    constexpr int L   = D / 4;     // uint2s (4 bf16) per node row
    constexpr int S   = 64 / L;    // nodes concurrently per wave
    constexpr int M   = 4;         // sequential nodes per subgroup
    constexpr int NPW = S * M;     // nodes per wave
    constexpr int NPB = NPW * 4;   // nodes per block (4 waves)
    constexpr int SP  = D + 4;     // LDS row stride (floats, 16B-aligned, pad)
    constexpr int COLT = DP / 16;
    __shared__ __align__(16) float hstage[NPB * SP];

    const int wave = threadIdx.x >> 6, lane = threadIdx.x & 63;
    const int sub = lane / L, cl = lane % L;
    const uint2* __restrict__ P2 = (const uint2*)P;
    const f32x4* __restrict__ R4 = (const f32x4*)Rres;
    const int base = blockIdx.x * NPB + wave * NPW + sub;

    // ---- gather phase ----
    #pragma unroll 1
    for (int m = 0; m < M; ++m) {
        const int n = base + m * S;
        const int lrow = wave * NPW + sub + m * S;   // local row in block
        f32x4 o = {0.f, 0.f, 0.f, 0.f};
        if (n < N) {
            int beg = rowptr[n], end = rowptr[n + 1];
            float4 a0 = {0, 0, 0, 0}, a1 = {0, 0, 0, 0}, a2 = {0, 0, 0, 0}, a3 = {0, 0, 0, 0};
            int j = beg;
            while (j < end && (j & 3)) { bfacc(a0, P2[(size_t)adj[j] * L + cl]); ++j; }
            for (; j + 8 <= end; j += 8) {
                int4 sA = *(const int4*)(adj + j);
                int4 sB = *(const int4*)(adj + j + 4);
                uint2 p0 = P2[(size_t)sA.x * L + cl];
                uint2 p1 = P2[(size_t)sA.y * L + cl];
                uint2 p2 = P2[(size_t)sA.z * L + cl];
                uint2 p3 = P2[(size_t)sA.w * L + cl];
                uint2 p4 = P2[(size_t)sB.x * L + cl];
                uint2 p5 = P2[(size_t)sB.y * L + cl];
                uint2 p6 = P2[(size_t)sB.z * L + cl];
                uint2 p7 = P2[(size_t)sB.w * L + cl];
                bfacc(a0, p0); bfacc(a1, p1); bfacc(a2, p2); bfacc(a3, p3);
                bfacc(a0, p4); bfacc(a1, p5); bfacc(a2, p6); bfacc(a3, p7);
            }
            if (j + 4 <= end) {
                int4 sA = *(const int4*)(adj + j);
                bfacc(a0, P2[(size_t)sA.x * L + cl]);
                bfacc(a1, P2[(size_t)sA.y * L + cl]);
                bfacc(a2, P2[(size_t)sA.z * L + cl]);
                bfacc(a3, P2[(size_t)sA.w * L + cl]);
                j += 4;
            }
            for (; j < end; ++j) bfacc(a0, P2[(size_t)adj[j] * L + cl]);
            int deg = end - beg;
            float inv = deg > 0 ? 1.0f / (float)deg : 0.0f;
            f32x4 r = R4[(size_t)n * L + cl];
            o.x = fmaxf((a0.x + a1.x + a2.x + a3.x) * inv + r.x, 0.0f);
            o.y = fmaxf((a0.y + a1.y + a2.y + a3.y) * inv + r.y, 0.0f);
            o.z = fmaxf((a0.z + a1.z + a2.z + a3.z) * inv + r.z, 0.0f);
            o.w = fmaxf((a0.w + a1.w + a2.w + a3.w) * inv + r.w, 0.0f);
        }
        *(f32x4*)&hstage[lrow * SP + cl * 4] = o;
    }
    __syncthreads();

    // ---- proj phase: NPB nodes, DIN=D -> DOUT=DP, A from LDS, W from global ----
    const int quad = lane >> 4, l16 = lane & 15;
    f32x4 zero = {0.f, 0.f, 0.f, 0.f};
    #pragma unroll
    for (int tile = 0; tile < NPB / 64; ++tile) {
        const int trow0 = wave * NPW + tile * 16;     // tile's first local row
        f32x4 accP[COLT], accR[COLT];
        #pragma unroll
        for (int t = 0; t < COLT; ++t) { accP[t] = zero; accR[t] = zero; }
        #pragma unroll
        for (int k0 = 0; k0 < D; k0 += 32) {
            const int kk = k0 + quad * 8;
            const float* hp = &hstage[(trow0 + l16) * SP + kk];
            bf16x8 ahi, alo;
            #pragma unroll
            for (int j = 0; j < 8; ++j) {
                float hv = hp[j];
                __bf16 hb = (__bf16)hv;
                ahi[j] = hb;
                alo[j] = (__bf16)(hv - (float)hb);
            }
            #pragma unroll
            for (int t = 0; t < COLT; ++t) {
                const int c = t * 16 + l16;
                const float* wlp = Wl + c * D + kk;
                const float* wrp = Wr + c * D + kk;
                float4 wl0 = *(const float4*)wlp;
                float4 wl1 = *(const float4*)(wlp + 4);
                float4 wr0 = *(const float4*)wrp;
                float4 wr1 = *(const float4*)(wrp + 4);
                float wlv[8] = {wl0.x, wl0.y, wl0.z, wl0.w, wl1.x, wl1.y, wl1.z, wl1.w};
                float wrv[8] = {wr0.x, wr0.y, wr0.z, wr0.w, wr1.x, wr1.y, wr1.z, wr1.w};
                bf16x8 bl, brh, brl;
                #pragma unroll
                for (int j = 0; j < 8; ++j) {
                    bl[j] = (__bf16)wlv[j];
                    __bf16 wh = (__bf16)wrv[j];
                    brh[j] = wh;
                    brl[j] = (__bf16)(wrv[j] - (float)wh);
                }
                accP[t] = __builtin_amdgcn_mfma_f32_16x16x32_bf16(ahi, bl,  accP[t], 0, 0, 0);
                accR[t] = __builtin_amdgcn_mfma_f32_16x16x32_bf16(ahi, brh, accR[t], 0, 0, 0);
                accR[t] = __builtin_amdgcn_mfma_f32_16x16x32_bf16(ahi, brl, accR[t], 0, 0, 0);
                accR[t] = __builtin_amdgcn_mfma_f32_16x16x32_bf16(alo, brh, accR[t], 0, 0, 0);
            }
        }
        // C/D layout: col = lane&15, row = quad*4 + reg  [m89-verified]
        #pragma unroll
        for (int t = 0; t < COLT; ++t) {
            const int c = t * 16 + l16;
            const float bc = bias[c];
            #pragma unroll
            for (int r = 0; r < 4; ++r) {
                int node = blockIdx.x * NPB + trow0 + quad * 4 + r;
                if (node < N) {
                    Pout[(size_t)node * DP + c] = f2bf_rne(accP[t][r]);
                    Rout[(size_t)node * DP + c] = accR[t][r] + bc;
                }
            }
        }
    }
}

// ---------------- final gather + linear heads (layer 3) ----------------

template<int DOUT> struct GatherCfg {
    static constexpr int L   = DOUT / 4;   // uint2s (4 bf16) per node row
    static constexpr int S   = 64 / L;     // nodes concurrently per wave
    static constexpr int M   = 4;          // sequential nodes per subgroup
    static constexpr int NPW = S * M;
    static constexpr int NPB = NPW * 4;    // 4 waves/block
};

template<int DOUT>
__global__ __launch_bounds__(256, 6) void gather_head(const unsigned short* __restrict__ P,
                                                      const int* __restrict__ rowptr,
                                                      const int* __restrict__ adj,
                                                      const float* __restrict__ Rres, int N,
                                                      const float* __restrict__ Wreg,
                                                      const float* __restrict__ breg,
                                                      const float* __restrict__ Wcls,
                                                      const float* __restrict__ bcls,
                                                      float* __restrict__ out) {
    using C = GatherCfg<DOUT>;
    constexpr int L = C::L, S = C::S, M = C::M;
    constexpr int NPW = C::NPW, NPB = C::NPB;
    const int wave = threadIdx.x >> 6, lane = threadIdx.x & 63;
    const int sub = lane / L, cl = lane % L;
    const uint2* __restrict__ P2 = (const uint2*)P;
    const float4* __restrict__ R4 = (const float4*)Rres;
    const int base = blockIdx.x * NPB + wave * NPW + sub;
    #pragma unroll 1
    for (int m = 0; m < M; ++m) {
        int n = base + m * S;
        if (n >= N) continue;
        int beg = rowptr[n], end = rowptr[n + 1];
        float4 a0 = {0, 0, 0, 0}, a1 = {0, 0, 0, 0}, a2 = {0, 0, 0, 0}, a3 = {0, 0, 0, 0};
        int j = beg;
        while (j < end && (j & 3)) { bfacc(a0, P2[(size_t)adj[j] * L + cl]); ++j; }
        for (; j + 8 <= end; j += 8) {
            int4 sA = *(const int4*)(adj + j);
            int4 sB = *(const int4*)(adj + j + 4);
            uint2 p0 = P2[(size_t)sA.x * L + cl];
            uint2 p1 = P2[(size_t)sA.y * L + cl];
            uint2 p2 = P2[(size_t)sA.z * L + cl];
            uint2 p3 = P2[(size_t)sA.w * L + cl];
            uint2 p4 = P2[(size_t)sB.x * L + cl];
            uint2 p5 = P2[(size_t)sB.y * L + cl];
            uint2 p6 = P2[(size_t)sB.z * L + cl];
            uint2 p7 = P2[(size_t)sB.w * L + cl];
            bfacc(a0, p0); bfacc(a1, p1); bfacc(a2, p2); bfacc(a3, p3);
            bfacc(a0, p4); bfacc(a1, p5); bfacc(a2, p6); bfacc(a3, p7);
        }
        if (j + 4 <= end) {
            int4 sA = *(const int4*)(adj + j);
            bfacc(a0, P2[(size_t)sA.x * L + cl]);
            bfacc(a1, P2[(size_t)sA.y * L + cl]);
            bfacc(a2, P2[(size_t)sA.z * L + cl]);
            bfacc(a3, P2[(size_t)sA.w * L + cl]);
            j += 4;
        }
        for (; j < end; ++j) bfacc(a0, P2[(size_t)adj[j] * L + cl]);
        int deg = end - beg;
        float inv = deg > 0 ? 1.0f / (float)deg : 0.0f;
        float4 r = R4[(size_t)n * L + cl];
        float4 o;
        o.x = fmaxf((a0.x + a1.x + a2.x + a3.x) * inv + r.x, 0.0f);
        o.y = fmaxf((a0.y + a1.y + a2.y + a3.y) * inv + r.y, 0.0f);
        o.z = fmaxf((a0.z + a1.z + a2.z + a3.z) * inv + r.z, 0.0f);
        o.w = fmaxf((a0.w + a1.w + a2.w + a3.w) * inv + r.w, 0.0f);
        // fused linear heads: per-lane partial dot (4 of 16 features),
        // 2-step shfl reduce across the 4-lane subgroup
        float4 wr = ((const float4*)Wreg)[cl];
        float4 wc = ((const float4*)Wcls)[cl];
        float pr = o.x * wr.x + o.y * wr.y + o.z * wr.z + o.w * wr.w;
        float pc = o.x * wc.x + o.y * wc.y + o.z * wc.z + o.w * wc.w;
        pr += __shfl_xor(pr, 1); pr += __shfl_xor(pr, 2);
        pc += __shfl_xor(pc, 1); pc += __shfl_xor(pc, 2);
        if (cl == 0) {
            out[n] = pr + breg[0];
            out[(size_t)N + n] = pc + bcls[0];
        }
    }
}

extern "C" void kernel_launch(void* const* d_in, const int* in_sizes, int n_in,
                              void* d_out, int out_size, void* d_ws, size_t ws_size,
                              hipStream_t stream) {
    const float* x    = (const float*)d_in[0];
    const int*   ei   = (const int*)d_in[1];
    const float* W1l  = (const float*)d_in[2];
    const float* b1l  = (const float*)d_in[3];
    const float* W1r  = (const float*)d_in[4];
    const float* W2l  = (const float*)d_in[5];
    const float* b2l  = (const float*)d_in[6];
    const float* W2r  = (const float*)d_in[7];
    const float* W3l  = (const float*)d_in[8];
    const float* b3l  = (const float*)d_in[9];
    const float* W3r  = (const float*)d_in[10];
    const float* Wreg = (const float*)d_in[11];
    const float* breg = (const float*)d_in[12];
    const float* Wcls = (const float*)d_in[13];
    const float* bcls = (const float*)d_in[14];

    const int N = in_sizes[0] / 128;
    const int E = in_sizes[1] / 2;
    const int* src = ei;
    const int* dst = ei + E;

    char* ws = (char*)d_ws;
    size_t off = 0;
    auto alloc = [&](size_t bytes) -> void* {
        void* p = ws + off;
        off += (bytes + 255) & ~(size_t)255;
        return p;
    };
    int*   rowptr = (int*)alloc((size_t)(N + 1) * 4);
    int*   bcnt   = (int*)alloc(1024);
    int*   bcur   = (int*)alloc(1024);
    int*   boff   = (int*)alloc(1028);
    int*   adj    = (int*)alloc((size_t)E * 4);
    unsigned short* A1 = (unsigned short*)alloc((size_t)N * 64 * 2);  // P1 bf16; A3 aliases
    unsigned short* A2 = (unsigned short*)alloc((size_t)N * 32 * 2);  // P2 bf16
    float* B      = (float*)alloc((size_t)N * 64 * 4);  // R1; doubles as T during CSR build
    float* C      = (float*)alloc((size_t)N * 32 * 4);  // R2
    float* D      = (float*)alloc((size_t)N * 16 * 4);  // R3
    int*   T      = (int*)B;                             // packed edges, E*4B <= N*64*4B
    unsigned short* A3 = A1;                             // P3 bf16 (A1 dead after layer 2)

    const int NBK = (N + 1023) >> 10;     // buckets (196; must be <= 256)

    // ---- CSR build ----
    hipMemsetAsync(bcnt, 0, 1024, stream);
    k_bcount<<<1024, 256, 0, stream>>>(dst, E, N, bcnt);
    k_bscan<<<1, 256, 0, stream>>>(bcnt, boff, bcur, NBK, E);
    k_bucket<<<(E + BTILE - 1) / BTILE, 256, 0, stream>>>(src, dst, E, N, boff, bcur, T, NBK);
    k_csr<<<NBK, 1024, 0, stream>>>(T, boff, rowptr, adj, N, E);

    const int PB = 64;   // nodes per proj_mfma block (4 waves x 16)

    // ---- layer 1 projection: x (128) -> P1,R1 (64) ----
    proj_mfma<128, 64><<<(N + PB - 1) / PB, 256, 0, stream>>>(x, W1l, W1r, b1l, A1, B, N);
    // ---- layer 1 gather + layer 2 projection fused: h1 never hits HBM ----
    gather_proj<64, 32><<<(N + 63) / 64, 256, 0, stream>>>(
        A1, rowptr, adj, B, W2l, W2r, b2l, A2, C, N);
    // ---- layer 2 gather + layer 3 projection fused: h2 never hits HBM ----
    gather_proj<32, 16><<<(N + 127) / 128, 256, 0, stream>>>(
        A2, rowptr, adj, C, W3l, W3r, b3l, A3, D, N);
    // ---- layer 3 gather + linear heads fused ----
    constexpr int G16 = GatherCfg<16>::NPB;
    gather_head<16><<<(N + G16 - 1) / G16, 256, 0, stream>>>(
        A3, rowptr, adj, D, N, Wreg, breg, Wcls, bcls, (float*)d_out);
}